// Round 2
// baseline (327.127 us; speedup 1.0000x reference)
//
#include <hip/hip_runtime.h>
#include <hip/hip_bf16.h>

// Problem constants
#define Dm   1024
#define Hh   16
#define HDq  64
#define DKV  512
#define KVHD 32
#define HID  128
#define Bb   2
#define Ll   2048
#define Ff   32

typedef _Float16 half8 __attribute__((ext_vector_type(8)));
typedef _Float16 half4v __attribute__((ext_vector_type(4)));
typedef float f32x4 __attribute__((ext_vector_type(4)));

__device__ __forceinline__ float gelu_exact(float x) {
    return 0.5f * x * (1.0f + erff(x * 0.70710678118654752f));
}

// ---------------------------------------------------------------------------
// kprep: blocks 0..255  : transpose+cvt [Wk|Wv] -> WT fp16 [1024 n][1024 k]
//        blocks 256..259: hidden MLPs -> gh_ws[b][128], tau_ws[b]
// ---------------------------------------------------------------------------
__global__ __launch_bounds__(256) void kprep(
        const float* __restrict__ h,
        const float* __restrict__ mu, const float* __restrict__ sigma,
        const float* __restrict__ Wk, const float* __restrict__ Wv,
        const float* __restrict__ tw1, const float* __restrict__ tb1,
        const float* __restrict__ tw2, const float* __restrict__ tb2,
        const float* __restrict__ dw1, const float* __restrict__ db1,
        _Float16* __restrict__ WT, float* __restrict__ gh_ws, float* __restrict__ tau_ws)
{
    const int bx = blockIdx.x, t = threadIdx.x;
    if (bx < 256) {
        __shared__ float T[64][68];
        const int kt = bx >> 4, nt = bx & 15;
        const int n0 = nt * 64, k0 = kt * 64;
        const float* src = (n0 < DKV) ? Wk : Wv;
        const int ncol0 = (n0 < DKV) ? n0 : n0 - DKV;
        const int rr = t >> 4, cc4 = (t & 15) * 4;
#pragma unroll
        for (int i = 0; i < 4; ++i) {
            const int kl = i * 16 + rr;
            float4 v = *(const float4*)(src + (size_t)(k0 + kl) * DKV + ncol0 + cc4);
            T[kl][cc4 + 0] = v.x; T[kl][cc4 + 1] = v.y;
            T[kl][cc4 + 2] = v.z; T[kl][cc4 + 3] = v.w;
        }
        __syncthreads();
#pragma unroll
        for (int i = 0; i < 4; ++i) {
            const int nl = i * 16 + rr;
            half4v o;
            o[0] = (_Float16)T[cc4 + 0][nl]; o[1] = (_Float16)T[cc4 + 1][nl];
            o[2] = (_Float16)T[cc4 + 2][nl]; o[3] = (_Float16)T[cc4 + 3][nl];
            *(half4v*)(WT + (size_t)(n0 + nl) * Dm + k0 + cc4) = o;
        }
    } else {
        const int id = bx - 256;
        const int b = id >> 1, which = id & 1;   // 0 = tau, 1 = delta
        __shared__ float hl[Dm];
        __shared__ float part[256];
        __shared__ float meanv;
        const float* hrow = h + ((size_t)b * Ll + (Ll - 1)) * Dm;
        for (int j = t; j < Dm; j += 256) hl[j] = hrow[j];
        if (t == 0) {
            float s = 0.f;
            const float* msrc = which ? mu : sigma;
            for (int f = 0; f < Ff; ++f) s += msrc[((size_t)b * Ll + (Ll - 1)) * Ff + f];
            s /= (float)Ff;
            meanv = which ? s : fmaxf(s, 1e-6f);
        }
        __syncthreads();
        const float* w1 = which ? dw1 : tw1;
        const int hid = t & 127, jj = t >> 7;
        float acc = 0.f;
        for (int j = jj; j < Dm; j += 2)
            acc += hl[j] * w1[(size_t)(j + 1) * HID + hid];
        part[t] = acc;
        __syncthreads();
        if (t < HID) {
            float a = part[t] + part[t + 128] + (which ? db1[t] : tb1[t]) + meanv * w1[t];
            float g = gelu_exact(a);
            if (which) gh_ws[b * HID + t] = g;
            else       part[t] = g * tw2[t];
        }
        __syncthreads();
        if (!which && t == 0) {
            float s = 0.f;
            for (int i = 0; i < HID; ++i) s += part[i];
            s += tb2[0];
            s = fminf(fmaxf(s, -3.f), 3.f);
            tau_ws[b] = expf(s);
        }
    }
}

// ---------------------------------------------------------------------------
// k_wcomb: w_comb[b][c] = tau[b]*Qc[b][c]/sqrt(32) + clip(delta_last[b][c])
// grid (4 col-tiles, B)
// ---------------------------------------------------------------------------
__global__ __launch_bounds__(256) void k_wcomb(
        const float* __restrict__ h, const float* __restrict__ Wq,
        const float* __restrict__ dw2, const float* __restrict__ db2,
        const float* __restrict__ gh_ws, const float* __restrict__ tau_ws,
        float* __restrict__ w_comb)
{
    const int ct = blockIdx.x, b = blockIdx.y;
    const int t = threadIdx.x;
    __shared__ float hl[Dm];
    __shared__ float gh[HID];
    __shared__ float red[256];
    const float* hrow = h + ((size_t)b * Ll + (Ll - 1)) * Dm;
    for (int j = t; j < Dm; j += 256) hl[j] = hrow[j];
    if (t < HID) gh[t] = gh_ws[b * HID + t];
    __syncthreads();
    const int cl = t & 127, js = t >> 7;
    const int c = ct * 128 + cl;
    const int colq = (c >> 5) * HDq + (c & 31);
    float q = 0.f;
    for (int j = js; j < Dm; j += 2)
        q += hl[j] * Wq[(size_t)j * Dm + colq];
    float dd = 0.f;
    for (int i = js * 64; i < js * 64 + 64; ++i)
        dd += gh[i] * dw2[(size_t)i * DKV + c];
    red[t] = q;
    __syncthreads();
    float qs = 0.f;
    if (t < 128) qs = red[t] + red[t + 128];
    __syncthreads();
    red[t] = dd;
    __syncthreads();
    if (t < 128) {
        float ds = red[t] + red[t + 128] + db2[ct * 128 + t];
        ds = fminf(fmaxf(ds, -5.f), 5.f);
        w_comb[b * DKV + ct * 128 + t] = tau_ws[b] * qs * 0.17677669529663687f + ds;
    }
}

// ---------------------------------------------------------------------------
// k_kv: fp16 MFMA GEMM  C[4096 x 1024] = h[4096 x 1024] @ [Wk|Wv]
// 128x128 tile, BK=32, 4 waves. ntile<4 -> fused logits; else store V fp16.
// ---------------------------------------------------------------------------
__global__ __launch_bounds__(256) void k_kv(
        const float* __restrict__ hmat, const _Float16* __restrict__ WT,
        const float* __restrict__ w_comb,
        _Float16* __restrict__ V16, float* __restrict__ logits)
{
    __shared__ __align__(16) char smem[32768];
    _Float16* As = (_Float16*)smem;             // [128][32]
    _Float16* Bs = (_Float16*)(smem + 8192);    // [128][32] (Bs[n][k])
    const int ntile = blockIdx.x, mtile = blockIdx.y;
    const int t = threadIdx.x;
    const int w = t >> 6, l = t & 63;
    const int m0 = mtile * 128, n0 = ntile * 128;
    const int wr = (w >> 1) * 64, wc = (w & 1) * 64;
    const int lrow = l & 15, kq = (l >> 4) * 8;

    const int ar = t >> 1;              // staging row 0..127
    const int ak = (t & 1) * 16;        // staging k offset (16 floats)
    const float* Ag = hmat + (size_t)(m0 + ar) * Dm + ak;
    const int nb0 = w * 32;             // B rows staged by this wave

    f32x4 acc[4][4] = {};

    for (int kt = 0; kt < 32; ++kt) {
        const int k0 = kt * 32;
        float4 a0 = *(const float4*)(Ag + k0 + 0);
        float4 a1 = *(const float4*)(Ag + k0 + 4);
        float4 a2 = *(const float4*)(Ag + k0 + 8);
        float4 a3 = *(const float4*)(Ag + k0 + 12);
#pragma unroll
        for (int cc = 0; cc < 2; ++cc) {
            const int nrow = nb0 + cc * 16 + (l >> 2);
            const _Float16* src = WT + (size_t)(n0 + nrow) * Dm + k0 + (l & 3) * 8;
            __builtin_amdgcn_global_load_lds(
                (const __attribute__((address_space(1))) unsigned int*)src,
                (__attribute__((address_space(3))) unsigned int*)(Bs + (nb0 + cc * 16) * 32),
                16, 0, 0);
        }
        half8 v0, v1;
        v0[0] = (_Float16)a0.x; v0[1] = (_Float16)a0.y; v0[2] = (_Float16)a0.z; v0[3] = (_Float16)a0.w;
        v0[4] = (_Float16)a1.x; v0[5] = (_Float16)a1.y; v0[6] = (_Float16)a1.z; v0[7] = (_Float16)a1.w;
        v1[0] = (_Float16)a2.x; v1[1] = (_Float16)a2.y; v1[2] = (_Float16)a2.z; v1[3] = (_Float16)a2.w;
        v1[4] = (_Float16)a3.x; v1[5] = (_Float16)a3.y; v1[6] = (_Float16)a3.z; v1[7] = (_Float16)a3.w;
        *(half8*)(As + ar * 32 + ak) = v0;
        *(half8*)(As + ar * 32 + ak + 8) = v1;
        __syncthreads();
        half8 af[4], bf[4];
#pragma unroll
        for (int mf = 0; mf < 4; ++mf)
            af[mf] = *(const half8*)(As + (wr + mf * 16 + lrow) * 32 + kq);
#pragma unroll
        for (int nf = 0; nf < 4; ++nf)
            bf[nf] = *(const half8*)(Bs + (wc + nf * 16 + lrow) * 32 + kq);
#pragma unroll
        for (int mf = 0; mf < 4; ++mf)
#pragma unroll
            for (int nf = 0; nf < 4; ++nf)
                acc[mf][nf] = __builtin_amdgcn_mfma_f32_16x16x32_f16(af[mf], bf[nf], acc[mf][nf], 0, 0, 0);
        __syncthreads();
    }

    const int b = mtile >> 4;
    if (ntile < 4) {
        // fused logits epilogue: logit[l] = sum_d K[l][d]*w_comb[d], clip +-50
        float wcv[4];
#pragma unroll
        for (int nf = 0; nf < 4; ++nf)
            wcv[nf] = w_comb[b * DKV + n0 + wc + nf * 16 + lrow];
#pragma unroll
        for (int mf = 0; mf < 4; ++mf)
#pragma unroll
            for (int hh = 0; hh < 2; ++hh) {
                float s[4];
#pragma unroll
                for (int r = 0; r < 4; ++r)
                    s[r] = acc[mf][2 * hh][r] * wcv[2 * hh] + acc[mf][2 * hh + 1][r] * wcv[2 * hh + 1];
#pragma unroll
                for (int mask = 1; mask <= 8; mask <<= 1)
#pragma unroll
                    for (int r = 0; r < 4; ++r)
                        s[r] += __shfl_xor(s[r], mask);
                if (lrow == 0) {
                    const int head = ((n0 + wc) >> 5) + hh;
#pragma unroll
                    for (int r = 0; r < 4; ++r) {
                        const int grow = m0 + wr + mf * 16 + (l >> 4) * 4 + r;
                        float val = fminf(fmaxf(s[r], -50.f), 50.f);
                        logits[((size_t)b * Hh + head) * Ll + (grow & (Ll - 1))] = val;
                    }
                }
            }
    } else {
        // V: stage fragments to per-wave LDS chunk, then coalesced fp16 dump
        _Float16* Cs = (_Float16*)smem + w * 4096;   // [64][64]
#pragma unroll
        for (int mf = 0; mf < 4; ++mf)
#pragma unroll
            for (int nf = 0; nf < 4; ++nf)
#pragma unroll
                for (int r = 0; r < 4; ++r)
                    Cs[(mf * 16 + (l >> 4) * 4 + r) * 64 + nf * 16 + lrow] = (_Float16)acc[mf][nf][r];
        const int vc0 = n0 - DKV + wc;
#pragma unroll
        for (int p = 0; p < 8; ++p) {
            const int r = p * 8 + (l >> 3);
            const int ch = (l & 7) * 8;
            half8 v = *(const half8*)(Cs + r * 64 + ch);
            const int grow = m0 + wr + r;
            *(half8*)(V16 + (size_t)grow * DKV + vc0 + ch) = v;
        }
    }
}

// ---------------------------------------------------------------------------
// k_attn: grid (8 splits, 32 bh). exp(logit-50) partial softmax + V-weighted sums
// ---------------------------------------------------------------------------
__global__ __launch_bounds__(256) void k_attn(
        const float* __restrict__ logits, const _Float16* __restrict__ V16,
        float* __restrict__ num_ws, float* __restrict__ den_ws)
{
    const int split = blockIdx.x, bh = blockIdx.y;
    const int b = bh >> 4, hd = bh & 15;
    const int t = threadIdx.x;
    __shared__ float p[256];
    __shared__ float red[256];
    __shared__ float part[8][32];
    const int l0 = split * 256;
    const float lv = logits[(size_t)bh * Ll + l0 + t];
    const float e = __expf(lv - 50.f);
    p[t] = e;
    red[t] = e;
    __syncthreads();
    for (int s = 128; s > 0; s >>= 1) {
        if (t < s) red[t] += red[t + s];
        __syncthreads();
    }
    if (t == 0) den_ws[bh * 8 + split] = red[0];
    const int kg = t >> 5, d = t & 31;
    const _Float16* Vb = V16 + (size_t)(b * Ll + l0 + kg * 32) * DKV + hd * 32 + d;
    float acc = 0.f;
#pragma unroll 4
    for (int j = 0; j < 32; ++j)
        acc += p[kg * 32 + j] * (float)Vb[(size_t)j * DKV];
    part[kg][d] = acc;
    __syncthreads();
    if (t < 32) {
        float s = 0.f;
#pragma unroll
        for (int g = 0; g < 8; ++g) s += part[g][t];
        num_ws[((size_t)bh * 8 + split) * 32 + t] = s;
    }
}

// ---------------------------------------------------------------------------
// k_out: finalize out_pre then (B x 512) @ (512 x 1024) + bias. grid (16, B)
// ---------------------------------------------------------------------------
__global__ __launch_bounds__(256) void k_out(
        const float* __restrict__ num_ws, const float* __restrict__ den_ws,
        const float* __restrict__ Wo, const float* __restrict__ bo,
        float* __restrict__ out)
{
    const int nt = blockIdx.x, b = blockIdx.y;
    const int t = threadIdx.x;
    __shared__ float op[DKV];
    __shared__ float dent[Hh];
    __shared__ float red[256];
    if (t < Hh) {
        float s = 0.f;
        for (int sp = 0; sp < 8; ++sp) s += den_ws[(b * Hh + t) * 8 + sp];
        dent[t] = s;
    }
    __syncthreads();
    for (int c = t; c < DKV; c += 256) {
        const int hd = c >> 5, d = c & 31;
        float s = 0.f;
#pragma unroll
        for (int sp = 0; sp < 8; ++sp)
            s += num_ws[(((size_t)b * Hh + hd) * 8 + sp) * 32 + d];
        op[c] = s / dent[hd];
    }
    __syncthreads();
    const int nl = t & 63, cg = t >> 6;
    const int n = nt * 64 + nl;
    float acc = 0.f;
    for (int c = cg * 128; c < cg * 128 + 128; ++c)
        acc += op[c] * Wo[(size_t)c * Dm + n];
    red[t] = acc;
    __syncthreads();
    if (t < 64) {
        float s = red[t] + red[64 + t] + red[128 + t] + red[192 + t];
        out[(size_t)b * Dm + nt * 64 + t] = bo[nt * 64 + t] + s;
    }
}

// ---------------------------------------------------------------------------
extern "C" void kernel_launch(void* const* d_in, const int* in_sizes, int n_in,
                              void* d_out, int out_size, void* d_ws, size_t ws_size,
                              hipStream_t stream) {
    const float* h      = (const float*)d_in[0];
    const float* mu     = (const float*)d_in[1];
    const float* sigma  = (const float*)d_in[2];
    const float* Wq     = (const float*)d_in[3];
    const float* Wk     = (const float*)d_in[4];
    const float* Wv     = (const float*)d_in[5];
    const float* Wo     = (const float*)d_in[6];
    const float* bo     = (const float*)d_in[7];
    const float* tau_w1 = (const float*)d_in[8];
    const float* tau_b1 = (const float*)d_in[9];
    const float* tau_w2 = (const float*)d_in[10];
    const float* tau_b2 = (const float*)d_in[11];
    const float* del_w1 = (const float*)d_in[12];
    const float* del_b1 = (const float*)d_in[13];
    const float* del_w2 = (const float*)d_in[14];
    const float* del_b2 = (const float*)d_in[15];
    float* out = (float*)d_out;

    // workspace layout: total ~6.3 MB
    _Float16* WT   = (_Float16*)d_ws;                      // 1024*1024 fp16 = 2 MB
    _Float16* V16  = WT + (size_t)Dm * Dm;                 // 4096*512 fp16  = 4 MB
    float* logits  = (float*)(V16 + (size_t)Bb * Ll * DKV);// 2*16*2048 f32  = 256 KB
    float* num_ws  = logits + (size_t)Bb * Hh * Ll;        // 32*8*32 f32
    float* den_ws  = num_ws + 32 * 8 * 32;                 // 256 f32
    float* gh_ws   = den_ws + 256;                         // 256 f32
    float* tau_ws  = gh_ws + 256;                          // 2 f32
    float* w_comb  = tau_ws + 2;                           // 1024 f32

    kprep<<<260, 256, 0, stream>>>(h, mu, sigma, Wk, Wv, tau_w1, tau_b1, tau_w2, tau_b2,
                                   del_w1, del_b1, WT, gh_ws, tau_ws);
    k_wcomb<<<dim3(4, Bb), 256, 0, stream>>>(h, Wq, del_w2, del_b2, gh_ws, tau_ws, w_comb);
    k_kv<<<dim3(8, 32), 256, 0, stream>>>(h, WT, w_comb, V16, logits);
    k_attn<<<dim3(8, 32), 256, 0, stream>>>(logits, V16, num_ws, den_ws);
    k_out<<<dim3(16, Bb), 256, 0, stream>>>(num_ws, den_ws, Wo, bo, out);
}

// Round 3
// 97.770 us; speedup vs baseline: 3.3459x; 3.3459x over previous
//
#include <hip/hip_runtime.h>
#include <hip/hip_bf16.h>

// Problem constants
#define Dm   1024
#define Hh   16
#define HDq  64
#define DKV  512
#define KVHD 32
#define HID  128
#define Bb   2
#define Ll   2048
#define Ff   32

typedef _Float16 half8 __attribute__((ext_vector_type(8)));
typedef _Float16 half4v __attribute__((ext_vector_type(4)));
typedef float f32x4 __attribute__((ext_vector_type(4)));

__device__ __forceinline__ float gelu_exact(float x) {
    return 0.5f * x * (1.0f + erff(x * 0.70710678118654752f));
}

// ---------------------------------------------------------------------------
// kprep:
//   blocks 0..255   : transpose+cvt [Wk|Wv] -> WT fp16 [1024 n][1024 k]
//   blocks 256..287 : w1 hidden partials (b, which, jsplit) -> hid_part
//   blocks 288..303 : Qc partials (b, jsplit) -> qc_part
// ---------------------------------------------------------------------------
__global__ __launch_bounds__(256) void kprep(
        const float* __restrict__ h,
        const float* __restrict__ Wk, const float* __restrict__ Wv,
        const float* __restrict__ Wq,
        const float* __restrict__ tw1, const float* __restrict__ dw1,
        _Float16* __restrict__ WT, float* __restrict__ hid_part,
        float* __restrict__ qc_part)
{
    const int bx = blockIdx.x, t = threadIdx.x;
    if (bx < 256) {
        __shared__ float T[64][65];
        const int kt = bx >> 4, nt = bx & 15;
        const int n0 = nt * 64, k0 = kt * 64;
        const float* src = (n0 < DKV) ? Wk : Wv;
        const int ncol0 = (n0 < DKV) ? n0 : n0 - DKV;
        const int rr = t >> 4, cc4 = (t & 15) * 4;
#pragma unroll
        for (int i = 0; i < 4; ++i) {
            const int kl = i * 16 + rr;
            float4 v = *(const float4*)(src + (size_t)(k0 + kl) * DKV + ncol0 + cc4);
            T[kl][cc4 + 0] = v.x; T[kl][cc4 + 1] = v.y;
            T[kl][cc4 + 2] = v.z; T[kl][cc4 + 3] = v.w;
        }
        __syncthreads();
#pragma unroll
        for (int i = 0; i < 4; ++i) {
            const int nl = i * 16 + rr;
            half4v o;
            o[0] = (_Float16)T[cc4 + 0][nl]; o[1] = (_Float16)T[cc4 + 1][nl];
            o[2] = (_Float16)T[cc4 + 2][nl]; o[3] = (_Float16)T[cc4 + 3][nl];
            *(half4v*)(WT + (size_t)(n0 + nl) * Dm + k0 + cc4) = o;
        }
    } else if (bx < 288) {
        // hidden-layer partials: acc over 128 h-rows for 128 hidden cols
        const int id = bx - 256;
        const int b = (id >> 4) & 1, which = (id >> 3) & 1, jsplit = id & 7;
        const float* w1 = which ? dw1 : tw1;
        __shared__ float hl[128];
        __shared__ float red[256];
        const float* hrow = h + ((size_t)b * Ll + (Ll - 1)) * Dm + jsplit * 128;
        if (t < 128) hl[t] = hrow[t];
        __syncthreads();
        const int col = t & 127, rg = t >> 7;
        const float* w1p = w1 + (size_t)(jsplit * 128 + rg + 1) * HID + col;
        float acc = 0.f;
#pragma unroll 8
        for (int p = 0; p < 64; ++p)
            acc += hl[p * 2 + rg] * w1p[(size_t)p * 2 * HID];
        red[t] = acc;
        __syncthreads();
        if (t < 128)
            hid_part[(((size_t)(b * 2 + which)) * 8 + jsplit) * HID + t] = red[t] + red[t + 128];
    } else {
        // Qc partials over Wq columns head*64+d (d<32)
        const int id = bx - 288;
        const int b = id >> 3, jsplit = id & 7;
        __shared__ float hl[128];
        const float* hrow = h + ((size_t)b * Ll + (Ll - 1)) * Dm + jsplit * 128;
        if (t < 128) hl[t] = hrow[t];
        __syncthreads();
        const int c0 = t, c1 = t + 256;
        const int colq0 = (c0 >> 5) * HDq + (c0 & 31);
        const int colq1 = (c1 >> 5) * HDq + (c1 & 31);
        const float* Wq0 = Wq + (size_t)(jsplit * 128) * Dm;
        float a0 = 0.f, a1 = 0.f;
#pragma unroll 8
        for (int j = 0; j < 128; ++j) {
            const float x = hl[j];
            a0 += x * Wq0[(size_t)j * Dm + colq0];
            a1 += x * Wq0[(size_t)j * Dm + colq1];
        }
        float* qp = qc_part + ((size_t)b * 8 + jsplit) * DKV;
        qp[c0] = a0;
        qp[c1] = a1;
    }
}

// ---------------------------------------------------------------------------
// k_wcomb: grid (Bb). finalize hidden -> tau, gh; delta matvec; combine.
// w_comb[b][c] = tau[b]*Qc[b][c]/sqrt(32) + clip(delta_last[b][c], +-5)
// ---------------------------------------------------------------------------
__global__ __launch_bounds__(256) void k_wcomb(
        const float* __restrict__ mu, const float* __restrict__ sigma,
        const float* __restrict__ tw1, const float* __restrict__ tb1,
        const float* __restrict__ tw2, const float* __restrict__ tb2,
        const float* __restrict__ dw1, const float* __restrict__ db1,
        const float* __restrict__ dw2, const float* __restrict__ db2,
        const float* __restrict__ hid_part, const float* __restrict__ qc_part,
        float* __restrict__ w_comb)
{
    const int b = blockIdx.x;
    const int t = threadIdx.x;
    __shared__ float gh[HID];
    __shared__ float red[256];
    __shared__ float s_tau, s_smean, s_mmean;

    if (t == 0) {
        float s = 0.f;
        for (int f = 0; f < Ff; ++f) s += sigma[((size_t)b * Ll + (Ll - 1)) * Ff + f];
        s_smean = fmaxf(s / (float)Ff, 1e-6f);
    }
    if (t == 64) {
        float s = 0.f;
        for (int f = 0; f < Ff; ++f) s += mu[((size_t)b * Ll + (Ll - 1)) * Ff + f];
        s_mmean = s / (float)Ff;
    }
    red[t] = 0.f;
    __syncthreads();

    if (t < 128) {
        // tau hidden
        float a = tb1[t] + s_smean * tw1[t];
#pragma unroll
        for (int s = 0; s < 8; ++s)
            a += hid_part[(((size_t)(b * 2 + 0)) * 8 + s) * HID + t];
        red[t] = gelu_exact(a) * tw2[t];
    } else {
        // delta hidden
        const int hh = t - 128;
        float a = db1[hh] + s_mmean * dw1[hh];
#pragma unroll
        for (int s = 0; s < 8; ++s)
            a += hid_part[(((size_t)(b * 2 + 1)) * 8 + s) * HID + hh];
        gh[hh] = gelu_exact(a);
    }
    __syncthreads();
    for (int s = 64; s > 0; s >>= 1) {
        if (t < s) red[t] += red[t + s];
        __syncthreads();
    }
    if (t == 0) {
        float s = red[0] + tb2[0];
        s = fminf(fmaxf(s, -3.f), 3.f);
        s_tau = expf(s);
    }
    __syncthreads();

    // delta = gh @ dw2 + db2 (clip +-5); combine with Qc
    const int c0 = t, c1 = t + 256;
    float d0 = db2[c0], d1 = db2[c1];
#pragma unroll 8
    for (int i = 0; i < HID; ++i) {
        const float x = gh[i];
        d0 += x * dw2[(size_t)i * DKV + c0];
        d1 += x * dw2[(size_t)i * DKV + c1];
    }
    d0 = fminf(fmaxf(d0, -5.f), 5.f);
    d1 = fminf(fmaxf(d1, -5.f), 5.f);
    float q0 = 0.f, q1 = 0.f;
#pragma unroll
    for (int s = 0; s < 8; ++s) {
        const float* qp = qc_part + ((size_t)b * 8 + s) * DKV;
        q0 += qp[c0];
        q1 += qp[c1];
    }
    const float inv_sqrt = 0.17677669529663687f;
    w_comb[(size_t)b * DKV + c0] = s_tau * q0 * inv_sqrt + d0;
    w_comb[(size_t)b * DKV + c1] = s_tau * q1 * inv_sqrt + d1;
}

// ---------------------------------------------------------------------------
// k_kv: fp16 MFMA GEMM  C[4096 x 1024] = h[4096 x 1024] @ [Wk|Wv]
// 128x128 tile, BK=32, 4 waves. ntile<4 -> fused logits; else store V fp16.
// ---------------------------------------------------------------------------
__global__ __launch_bounds__(256) void k_kv(
        const float* __restrict__ hmat, const _Float16* __restrict__ WT,
        const float* __restrict__ w_comb,
        _Float16* __restrict__ V16, float* __restrict__ logits)
{
    __shared__ __align__(16) char smem[32768];
    _Float16* As = (_Float16*)smem;             // [128][32]
    _Float16* Bs = (_Float16*)(smem + 8192);    // [128][32] (Bs[n][k])
    const int ntile = blockIdx.x, mtile = blockIdx.y;
    const int t = threadIdx.x;
    const int w = t >> 6, l = t & 63;
    const int m0 = mtile * 128, n0 = ntile * 128;
    const int wr = (w >> 1) * 64, wc = (w & 1) * 64;
    const int lrow = l & 15, kq = (l >> 4) * 8;

    const int ar = t >> 1;              // staging row 0..127
    const int ak = (t & 1) * 16;        // staging k offset (16 floats)
    const float* Ag = hmat + (size_t)(m0 + ar) * Dm + ak;
    const int nb0 = w * 32;             // B rows staged by this wave

    f32x4 acc[4][4] = {};

    for (int kt = 0; kt < 32; ++kt) {
        const int k0 = kt * 32;
        float4 a0 = *(const float4*)(Ag + k0 + 0);
        float4 a1 = *(const float4*)(Ag + k0 + 4);
        float4 a2 = *(const float4*)(Ag + k0 + 8);
        float4 a3 = *(const float4*)(Ag + k0 + 12);
#pragma unroll
        for (int cc = 0; cc < 2; ++cc) {
            const int nrow = nb0 + cc * 16 + (l >> 2);
            const _Float16* src = WT + (size_t)(n0 + nrow) * Dm + k0 + (l & 3) * 8;
            __builtin_amdgcn_global_load_lds(
                (const __attribute__((address_space(1))) unsigned int*)src,
                (__attribute__((address_space(3))) unsigned int*)(Bs + (nb0 + cc * 16) * 32),
                16, 0, 0);
        }
        half8 v0, v1;
        v0[0] = (_Float16)a0.x; v0[1] = (_Float16)a0.y; v0[2] = (_Float16)a0.z; v0[3] = (_Float16)a0.w;
        v0[4] = (_Float16)a1.x; v0[5] = (_Float16)a1.y; v0[6] = (_Float16)a1.z; v0[7] = (_Float16)a1.w;
        v1[0] = (_Float16)a2.x; v1[1] = (_Float16)a2.y; v1[2] = (_Float16)a2.z; v1[3] = (_Float16)a2.w;
        v1[4] = (_Float16)a3.x; v1[5] = (_Float16)a3.y; v1[6] = (_Float16)a3.z; v1[7] = (_Float16)a3.w;
        *(half8*)(As + ar * 32 + ak) = v0;
        *(half8*)(As + ar * 32 + ak + 8) = v1;
        __syncthreads();
        half8 af[4], bf[4];
#pragma unroll
        for (int mf = 0; mf < 4; ++mf)
            af[mf] = *(const half8*)(As + (wr + mf * 16 + lrow) * 32 + kq);
#pragma unroll
        for (int nf = 0; nf < 4; ++nf)
            bf[nf] = *(const half8*)(Bs + (wc + nf * 16 + lrow) * 32 + kq);
#pragma unroll
        for (int mf = 0; mf < 4; ++mf)
#pragma unroll
            for (int nf = 0; nf < 4; ++nf)
                acc[mf][nf] = __builtin_amdgcn_mfma_f32_16x16x32_f16(af[mf], bf[nf], acc[mf][nf], 0, 0, 0);
        __syncthreads();
    }

    const int b = mtile >> 4;
    if (ntile < 4) {
        // fused logits epilogue: logit[l] = sum_d K[l][d]*w_comb[d], clip +-50
        float wcv[4];
#pragma unroll
        for (int nf = 0; nf < 4; ++nf)
            wcv[nf] = w_comb[b * DKV + n0 + wc + nf * 16 + lrow];
#pragma unroll
        for (int mf = 0; mf < 4; ++mf)
#pragma unroll
            for (int hh = 0; hh < 2; ++hh) {
                float s[4];
#pragma unroll
                for (int r = 0; r < 4; ++r)
                    s[r] = acc[mf][2 * hh][r] * wcv[2 * hh] + acc[mf][2 * hh + 1][r] * wcv[2 * hh + 1];
#pragma unroll
                for (int mask = 1; mask <= 8; mask <<= 1)
#pragma unroll
                    for (int r = 0; r < 4; ++r)
                        s[r] += __shfl_xor(s[r], mask);
                if (lrow == 0) {
                    const int head = ((n0 + wc) >> 5) + hh;
#pragma unroll
                    for (int r = 0; r < 4; ++r) {
                        const int grow = m0 + wr + mf * 16 + (l >> 4) * 4 + r;
                        float val = fminf(fmaxf(s[r], -50.f), 50.f);
                        logits[((size_t)b * Hh + head) * Ll + (grow & (Ll - 1))] = val;
                    }
                }
            }
    } else {
        // V: stage fragments to per-wave LDS chunk, then coalesced fp16 dump
        _Float16* Cs = (_Float16*)smem + w * 4096;   // [64][64]
#pragma unroll
        for (int mf = 0; mf < 4; ++mf)
#pragma unroll
            for (int nf = 0; nf < 4; ++nf)
#pragma unroll
                for (int r = 0; r < 4; ++r)
                    Cs[(mf * 16 + (l >> 4) * 4 + r) * 64 + nf * 16 + lrow] = (_Float16)acc[mf][nf][r];
        const int vc0 = n0 - DKV + wc;
#pragma unroll
        for (int p = 0; p < 8; ++p) {
            const int r = p * 8 + (l >> 3);
            const int ch = (l & 7) * 8;
            half8 v = *(const half8*)(Cs + r * 64 + ch);
            const int grow = m0 + wr + r;
            *(half8*)(V16 + (size_t)grow * DKV + vc0 + ch) = v;
        }
    }
}

// ---------------------------------------------------------------------------
// k_attn: grid (8 splits, 32 bh). exp(logit-50) partial softmax + V-weighted sums
// ---------------------------------------------------------------------------
__global__ __launch_bounds__(256) void k_attn(
        const float* __restrict__ logits, const _Float16* __restrict__ V16,
        float* __restrict__ num_ws, float* __restrict__ den_ws)
{
    const int split = blockIdx.x, bh = blockIdx.y;
    const int b = bh >> 4, hd = bh & 15;
    const int t = threadIdx.x;
    __shared__ float p[256];
    __shared__ float red[256];
    __shared__ float part[8][32];
    const int l0 = split * 256;
    const float lv = logits[(size_t)bh * Ll + l0 + t];
    const float e = __expf(lv - 50.f);
    p[t] = e;
    red[t] = e;
    __syncthreads();
    for (int s = 128; s > 0; s >>= 1) {
        if (t < s) red[t] += red[t + s];
        __syncthreads();
    }
    if (t == 0) den_ws[bh * 8 + split] = red[0];
    const int kg = t >> 5, d = t & 31;
    const _Float16* Vb = V16 + (size_t)(b * Ll + l0 + kg * 32) * DKV + hd * 32 + d;
    float acc = 0.f;
#pragma unroll 4
    for (int j = 0; j < 32; ++j)
        acc += p[kg * 32 + j] * (float)Vb[(size_t)j * DKV];
    part[kg][d] = acc;
    __syncthreads();
    if (t < 32) {
        float s = 0.f;
#pragma unroll
        for (int g = 0; g < 8; ++g) s += part[g][t];
        num_ws[((size_t)bh * 8 + split) * 32 + t] = s;
    }
}

// ---------------------------------------------------------------------------
// k_out: finalize out_pre then (B x 512) @ (512 x 1024) + bias. grid (16, B)
// ---------------------------------------------------------------------------
__global__ __launch_bounds__(256) void k_out(
        const float* __restrict__ num_ws, const float* __restrict__ den_ws,
        const float* __restrict__ Wo, const float* __restrict__ bo,
        float* __restrict__ out)
{
    const int nt = blockIdx.x, b = blockIdx.y;
    const int t = threadIdx.x;
    __shared__ float op[DKV];
    __shared__ float dent[Hh];
    __shared__ float red[256];
    if (t < Hh) {
        float s = 0.f;
        for (int sp = 0; sp < 8; ++sp) s += den_ws[(b * Hh + t) * 8 + sp];
        dent[t] = s;
    }
    __syncthreads();
    for (int c = t; c < DKV; c += 256) {
        const int hd = c >> 5, d = c & 31;
        float s = 0.f;
#pragma unroll
        for (int sp = 0; sp < 8; ++sp)
            s += num_ws[(((size_t)b * Hh + hd) * 8 + sp) * 32 + d];
        op[c] = s / dent[hd];
    }
    __syncthreads();
    const int nl = t & 63, cg = t >> 6;
    const int n = nt * 64 + nl;
    float acc = 0.f;
    for (int c = cg * 128; c < cg * 128 + 128; ++c)
        acc += op[c] * Wo[(size_t)c * Dm + n];
    red[t] = acc;
    __syncthreads();
    if (t < 64) {
        float s = red[t] + red[64 + t] + red[128 + t] + red[192 + t];
        out[(size_t)b * Dm + nt * 64 + t] = bo[nt * 64 + t] + s;
    }
}

// ---------------------------------------------------------------------------
extern "C" void kernel_launch(void* const* d_in, const int* in_sizes, int n_in,
                              void* d_out, int out_size, void* d_ws, size_t ws_size,
                              hipStream_t stream) {
    const float* h      = (const float*)d_in[0];
    const float* mu     = (const float*)d_in[1];
    const float* sigma  = (const float*)d_in[2];
    const float* Wq     = (const float*)d_in[3];
    const float* Wk     = (const float*)d_in[4];
    const float* Wv     = (const float*)d_in[5];
    const float* Wo     = (const float*)d_in[6];
    const float* bo     = (const float*)d_in[7];
    const float* tau_w1 = (const float*)d_in[8];
    const float* tau_b1 = (const float*)d_in[9];
    const float* tau_w2 = (const float*)d_in[10];
    const float* tau_b2 = (const float*)d_in[11];
    const float* del_w1 = (const float*)d_in[12];
    const float* del_b1 = (const float*)d_in[13];
    const float* del_w2 = (const float*)d_in[14];
    const float* del_b2 = (const float*)d_in[15];
    float* out = (float*)d_out;

    // workspace layout: ~6.4 MB
    _Float16* WT   = (_Float16*)d_ws;                      // 1024*1024 fp16 = 2 MB
    _Float16* V16  = WT + (size_t)Dm * Dm;                 // 4096*512 fp16  = 4 MB
    float* logits  = (float*)(V16 + (size_t)Bb * Ll * DKV);// 2*16*2048 f32  = 256 KB
    float* num_ws  = logits + (size_t)Bb * Hh * Ll;        // 32*8*32 f32
    float* den_ws  = num_ws + 32 * 8 * 32;                 // 256 f32
    float* hid_part= den_ws + 256;                         // 2*2*8*128 = 4096 f32
    float* qc_part = hid_part + 4096;                      // 2*8*512   = 8192 f32
    float* w_comb  = qc_part + 8192;                       // 1024 f32

    kprep<<<304, 256, 0, stream>>>(h, Wk, Wv, Wq, tau_w1, del_w1, WT, hid_part, qc_part);
    k_wcomb<<<Bb, 256, 0, stream>>>(mu, sigma, tau_w1, tau_b1, tau_w2, tau_b2,
                                    del_w1, del_b1, del_w2, del_b2,
                                    hid_part, qc_part, w_comb);
    k_kv<<<dim3(8, 32), 256, 0, stream>>>(h, WT, w_comb, V16, logits);
    k_attn<<<dim3(8, 32), 256, 0, stream>>>(logits, V16, num_ws, den_ws);
    k_out<<<dim3(16, Bb), 256, 0, stream>>>(num_ws, den_ws, Wo, bo, out);
}